// Round 1
// 190.746 us; speedup vs baseline: 1.0355x; 1.0355x over previous
//
#include <hip/hip_runtime.h>
#include <hip/hip_bf16.h>

constexpr int N_NODES = 100000;
constexpr int N_EDGES = 600000;
constexpr int D = 128;          // feature dim; OUT_DIM is also 128
constexpr int CAP = 32;         // slots per row; max degree ~18 (Poisson l=6, 600K/100K)

// ---------------- workspace layout (bytes) ----------------
constexpr size_t X16_OFF  = 0;          // x bf16: 100000*128*2 = 25,600,000
constexpr size_t WP_OFF   = 25600000;   // packed W bf16: 65,536
constexpr size_t CNT_OFF  = 25665536;   // cnt: 100000 ints = 400,000
constexpr size_t BINS_OFF = 26065536;   // int2 x 100000*32 = 25.6 MB (end ~51.7 MB)

typedef __attribute__((ext_vector_type(8))) short short8;
typedef __attribute__((ext_vector_type(4))) float float4v;

__device__ inline unsigned short f2bf(float f) {
    union { float f; unsigned int u; } v; v.f = f;
    unsigned int u = v.u + 0x7fffu + ((v.u >> 16) & 1u);  // RNE
    return (unsigned short)(u >> 16);
}
__device__ inline float bf2f(unsigned int lo16) {
    union { unsigned int u; float f; } v; v.u = lo16 << 16;
    return v.f;
}

// ---------------------------------------------------------------------------
// Prep (one dispatch, grid-stride; cnt pre-zeroed by memset node):
//   (a) bin edges into positional per-row slots (padded CSR, no scan)
//   (b) pack W into B-fragment order
//   (c) cast x fp32->bf16
// Wp B-fragment order for mfma_f32_16x16x32_bf16:
//   b_frag[lane][j] = W[s*32 + (lane>>4)*8 + j][jt*16 + (lane&15)]
//   at linear index ((s*8 + jt)*64 + lane)*8 + j.
// ---------------------------------------------------------------------------
__global__ __launch_bounds__(256) void prep_kernel(
    const float* __restrict__ x, uint4* __restrict__ x16,
    const float* __restrict__ W, unsigned short* __restrict__ Wp,
    const int* __restrict__ rows, const int* __restrict__ cols,
    const float* __restrict__ vals,
    int* __restrict__ cnt, int2* __restrict__ bins)
{
    const int tid = blockIdx.x * 256 + threadIdx.x;
    const int T   = gridDim.x * 256;

    // (a) positional binning
    for (int e = tid; e < N_EDGES; e += T) {
        int r = rows[e];
        int pos = atomicAdd(&cnt[r], 1);
        if (pos < CAP)
            bins[(size_t)r * CAP + pos] = make_int2(cols[e], __float_as_int(vals[e]));
    }

    // (b) pack W
    for (int idx = tid; idx < 8 * 8 * 64 * 8; idx += T) {
        int j    = idx & 7;
        int lane = (idx >> 3) & 63;
        int jt   = (idx >> 9) & 7;
        int s    = idx >> 12;
        int k = s * 32 + (lane >> 4) * 8 + j;
        int n = jt * 16 + (lane & 15);
        Wp[idx] = f2bf(W[k * 128 + n]);
    }

    // (c) cast x
    for (int g = tid; g < N_NODES * D / 8; g += T) {
        const float4* xp = reinterpret_cast<const float4*>(x + (size_t)g * 8);
        float4 a = xp[0], c = xp[1];
        uint4 o;
        o.x = (unsigned int)f2bf(a.x) | ((unsigned int)f2bf(a.y) << 16);
        o.y = (unsigned int)f2bf(a.z) | ((unsigned int)f2bf(a.w) << 16);
        o.z = (unsigned int)f2bf(c.x) | ((unsigned int)f2bf(c.y) << 16);
        o.w = (unsigned int)f2bf(c.z) | ((unsigned int)f2bf(c.w) << 16);
        x16[g] = o;
    }
}

// ---------------------------------------------------------------------------
// Fused aggregate + GEMM + relu.
// R8: block = 2 waves = 32 rows (was 4 waves/64 rows). Grid 1563 -> 3125 for
// finer fill granularity + load balance (OccupancyPercent was 29.7%; Phase A
// duration variance on 64-row tiles left the machine half-empty).
//
// Phase A (R4-proven structure, low VGPR): wave splits into 4 groups of 16
// lanes; group g processes its 4 rows (m_local = t*4+g) SEQUENTIALLY — only
// one row's state live at a time (low VGPR => high occupancy).
// R8 chain-shorteners:
//   - cnt[] for all 4 rows prefetched BEFORE the row loop (removes one
//     dependent latency per row).
//   - edge loop is ALWAYS 4-wide predicated: indices clamped to dend-1
//     (duplicate loads of the last real edge, same cache line, always
//     in-bounds) and duplicate lanes' val zeroed. Kills the 1-wide serial
//     remainder loop that cost ~2 extra full-latency round trips per row.
// [R7 lesson: interleaving the 4 rows inflated VGPR to 72, occupancy to 23%,
//  and cost +20 µs — do not re-introduce.]
//
// Phase B: mfma_f32_16x16x32_bf16; A s=0..3 from LDS (= h rows), s=4..7
// straight from global x16; B from pre-packed Wp (lane-contiguous 16B, L2).
// C/D layout: col = lane&15, row = (lane>>4)*4 + reg  [m89-verified].
// ---------------------------------------------------------------------------
__global__ __launch_bounds__(128) void fused_agg_gemm_kernel(
    const uint4* __restrict__ x16v,
    const unsigned short* __restrict__ x16s,
    const int* __restrict__ cnt,
    const int2* __restrict__ bins,
    const unsigned short* __restrict__ Wp,
    float* __restrict__ out)
{
    __shared__ uint4 lds4[2 * 256];   // wave*256 + s*64 + m*4 + q  (8 KB)

    const int tid  = threadIdx.x;
    const int wave = tid >> 6;
    const int lane = tid & 63;
    const int row0 = blockIdx.x * 32 + wave * 16;

    // ---------------- Phase A: aggregate 16 rows into LDS ----------------
    {
        const int g   = lane >> 4;      // group 0..3
        const int gl  = lane & 15;      // lane in group
        const int s_w = gl >> 2;
        const int q_w = gl & 3;

        // prefetch degree for all 4 rows of this group (independent loads)
        int dends[4];
        #pragma unroll
        for (int t = 0; t < 4; t++) {
            const int n = row0 + t * 4 + g;
            int d = (n < N_NODES) ? cnt[n] : 0;
            dends[t] = d > CAP ? CAP : d;
        }

        for (int t = 0; t < 4; t++) {
            const int m_local = t * 4 + g;
            const int n = row0 + m_local;
            float a0=0.f,a1=0.f,a2=0.f,a3=0.f,a4=0.f,a5=0.f,a6=0.f,a7=0.f;
            if (n < N_NODES) {
                const int2* bp = bins + (size_t)n * CAP;
                const int dend = dends[t];
                for (int i = 0; i < dend; i += 4) {
                    // always 4-wide: clamp idx into [0, dend), zero dup vals
                    const int i1 = (i + 1 < dend) ? i + 1 : dend - 1;
                    const int i2 = (i + 2 < dend) ? i + 2 : dend - 1;
                    const int i3 = (i + 3 < dend) ? i + 3 : dend - 1;
                    int2 e0 = bp[i];
                    int2 e1 = bp[i1];
                    int2 e2 = bp[i2];
                    int2 e3 = bp[i3];
                    uint4 p0 = x16v[(size_t)e0.x * 16 + gl];
                    uint4 p1 = x16v[(size_t)e1.x * 16 + gl];
                    uint4 p2 = x16v[(size_t)e2.x * 16 + gl];
                    uint4 p3 = x16v[(size_t)e3.x * 16 + gl];
                    float v0 = __int_as_float(e0.y);
                    float v1 = (i + 1 < dend) ? __int_as_float(e1.y) : 0.f;
                    float v2 = (i + 2 < dend) ? __int_as_float(e2.y) : 0.f;
                    float v3 = (i + 3 < dend) ? __int_as_float(e3.y) : 0.f;
                    a0 += v0 * bf2f(p0.x & 0xffffu) + v1 * bf2f(p1.x & 0xffffu)
                        + v2 * bf2f(p2.x & 0xffffu) + v3 * bf2f(p3.x & 0xffffu);
                    a1 += v0 * bf2f(p0.x >> 16)     + v1 * bf2f(p1.x >> 16)
                        + v2 * bf2f(p2.x >> 16)     + v3 * bf2f(p3.x >> 16);
                    a2 += v0 * bf2f(p0.y & 0xffffu) + v1 * bf2f(p1.y & 0xffffu)
                        + v2 * bf2f(p2.y & 0xffffu) + v3 * bf2f(p3.y & 0xffffu);
                    a3 += v0 * bf2f(p0.y >> 16)     + v1 * bf2f(p1.y >> 16)
                        + v2 * bf2f(p2.y >> 16)     + v3 * bf2f(p3.y >> 16);
                    a4 += v0 * bf2f(p0.z & 0xffffu) + v1 * bf2f(p1.z & 0xffffu)
                        + v2 * bf2f(p2.z & 0xffffu) + v3 * bf2f(p3.z & 0xffffu);
                    a5 += v0 * bf2f(p0.z >> 16)     + v1 * bf2f(p1.z >> 16)
                        + v2 * bf2f(p2.z >> 16)     + v3 * bf2f(p3.z >> 16);
                    a6 += v0 * bf2f(p0.w & 0xffffu) + v1 * bf2f(p1.w & 0xffffu)
                        + v2 * bf2f(p2.w & 0xffffu) + v3 * bf2f(p3.w & 0xffffu);
                    a7 += v0 * bf2f(p0.w >> 16)     + v1 * bf2f(p1.w >> 16)
                        + v2 * bf2f(p2.w >> 16)     + v3 * bf2f(p3.w >> 16);
                }
            }
            uint4 o;
            o.x = (unsigned int)f2bf(a0) | ((unsigned int)f2bf(a1) << 16);
            o.y = (unsigned int)f2bf(a2) | ((unsigned int)f2bf(a3) << 16);
            o.z = (unsigned int)f2bf(a4) | ((unsigned int)f2bf(a5) << 16);
            o.w = (unsigned int)f2bf(a6) | ((unsigned int)f2bf(a7) << 16);
            lds4[wave * 256 + s_w * 64 + m_local * 4 + q_w] = o;
        }
    }
    __syncthreads();

    // ---------------- Phase B: MFMA GEMM + relu ----------------
    const int m    = lane & 15;
    const int quad = lane >> 4;

    int arow = row0 + m;
    if (arow >= N_NODES) arow = N_NODES - 1;   // clamped dup load; stores guarded
    const unsigned short* xrow = x16s + (size_t)arow * D + quad * 8;

    float4v acc[8];
    #pragma unroll
    for (int jt = 0; jt < 8; jt++) acc[jt] = (float4v){0.f, 0.f, 0.f, 0.f};

    #pragma unroll
    for (int s = 0; s < 8; s++) {
        short8 a;
        if (s < 4)
            a = *reinterpret_cast<const short8*>(&lds4[wave * 256 + s * 64 + m * 4 + quad]);
        else
            a = *reinterpret_cast<const short8*>(xrow + (s - 4) * 32);
        #pragma unroll
        for (int jt = 0; jt < 8; jt++) {
            short8 b = *reinterpret_cast<const short8*>(
                Wp + ((size_t)((s * 8 + jt) * 64 + lane)) * 8);
            acc[jt] = __builtin_amdgcn_mfma_f32_16x16x32_bf16(a, b, acc[jt], 0, 0, 0);
        }
    }

    #pragma unroll
    for (int reg = 0; reg < 4; reg++) {
        int r = row0 + quad * 4 + reg;
        if (r < N_NODES) {
            float* orow = out + (size_t)r * D;
            #pragma unroll
            for (int jt = 0; jt < 8; jt++)
                orow[jt * 16 + m] = fmaxf(acc[jt][reg], 0.f);
        }
    }
}

// ---------------------------------------------------------------------------
extern "C" void kernel_launch(void* const* d_in, const int* in_sizes, int n_in,
                              void* d_out, int out_size, void* d_ws, size_t ws_size,
                              hipStream_t stream)
{
    const float* x    = (const float*)d_in[0];
    const int*   rows = (const int*)  d_in[1];
    const int*   cols = (const int*)  d_in[2];
    const float* vals = (const float*)d_in[3];
    const float* W    = (const float*)d_in[4];
    float* out = (float*)d_out;

    char* ws = (char*)d_ws;
    uint4*          x16v = (uint4*)         (ws + X16_OFF);
    unsigned short* x16s = (unsigned short*)(ws + X16_OFF);
    unsigned short* Wp   = (unsigned short*)(ws + WP_OFF);
    int*            cnt  = (int*)           (ws + CNT_OFF);
    int2*           bins = (int2*)          (ws + BINS_OFF);

    hipMemsetAsync(cnt, 0, N_NODES * sizeof(int), stream);
    prep_kernel<<<2048, 256, 0, stream>>>(x, x16v, W, Wp, rows, cols, vals, cnt, bins);
    fused_agg_gemm_kernel<<<(N_NODES + 31) / 32, 128, 0, stream>>>(
        x16v, x16s, cnt, bins, Wp, out);
}

// Round 2
// 185.160 us; speedup vs baseline: 1.0668x; 1.0302x over previous
//
#include <hip/hip_runtime.h>
#include <hip/hip_bf16.h>

constexpr int N_NODES = 100000;
constexpr int N_EDGES = 600000;
constexpr int D = 128;          // feature dim; OUT_DIM is also 128
constexpr int CAP = 32;         // slots per row; max degree ~18 (Poisson l=6, 600K/100K)

// ---------------- workspace layout (bytes) ----------------
constexpr size_t X16_OFF  = 0;          // x bf16: 100000*128*2 = 25,600,000
constexpr size_t WP_OFF   = 25600000;   // packed W bf16: 65,536
constexpr size_t CNT_OFF  = 25665536;   // cnt: 100000 ints = 400,000
constexpr size_t BINS_OFF = 26065536;   // int2 x 100000*32 = 25.6 MB (end ~51.7 MB)

typedef __attribute__((ext_vector_type(8))) short short8;
typedef __attribute__((ext_vector_type(4))) float float4v;

__device__ inline unsigned short f2bf(float f) {
    union { float f; unsigned int u; } v; v.f = f;
    unsigned int u = v.u + 0x7fffu + ((v.u >> 16) & 1u);  // RNE
    return (unsigned short)(u >> 16);
}
__device__ inline float bf2f(unsigned int lo16) {
    union { unsigned int u; float f; } v; v.u = lo16 << 16;
    return v.f;
}

// ---------------------------------------------------------------------------
// Prep (one dispatch, grid-stride; cnt pre-zeroed by memset node):
//   (a) bin edges into positional per-row slots (padded CSR, no scan)
//   (b) pack W into B-fragment order
//   (c) cast x fp32->bf16
// Wp B-fragment order for mfma_f32_16x16x32_bf16:
//   b_frag[lane][j] = W[s*32 + (lane>>4)*8 + j][jt*16 + (lane&15)]
//   at linear index ((s*8 + jt)*64 + lane)*8 + j.
// ---------------------------------------------------------------------------
__global__ __launch_bounds__(256) void prep_kernel(
    const float* __restrict__ x, uint4* __restrict__ x16,
    const float* __restrict__ W, unsigned short* __restrict__ Wp,
    const int* __restrict__ rows, const int* __restrict__ cols,
    const float* __restrict__ vals,
    int* __restrict__ cnt, int2* __restrict__ bins)
{
    const int tid = blockIdx.x * 256 + threadIdx.x;
    const int T   = gridDim.x * 256;

    // (a) positional binning
    for (int e = tid; e < N_EDGES; e += T) {
        int r = rows[e];
        int pos = atomicAdd(&cnt[r], 1);
        if (pos < CAP)
            bins[(size_t)r * CAP + pos] = make_int2(cols[e], __float_as_int(vals[e]));
    }

    // (b) pack W
    for (int idx = tid; idx < 8 * 8 * 64 * 8; idx += T) {
        int j    = idx & 7;
        int lane = (idx >> 3) & 63;
        int jt   = (idx >> 9) & 7;
        int s    = idx >> 12;
        int k = s * 32 + (lane >> 4) * 8 + j;
        int n = jt * 16 + (lane & 15);
        Wp[idx] = f2bf(W[k * 128 + n]);
    }

    // (c) cast x
    for (int g = tid; g < N_NODES * D / 8; g += T) {
        const float4* xp = reinterpret_cast<const float4*>(x + (size_t)g * 8);
        float4 a = xp[0], c = xp[1];
        uint4 o;
        o.x = (unsigned int)f2bf(a.x) | ((unsigned int)f2bf(a.y) << 16);
        o.y = (unsigned int)f2bf(a.z) | ((unsigned int)f2bf(a.w) << 16);
        o.z = (unsigned int)f2bf(c.x) | ((unsigned int)f2bf(c.y) << 16);
        o.w = (unsigned int)f2bf(c.z) | ((unsigned int)f2bf(c.w) << 16);
        x16[g] = o;
    }
}

// ---------------------------------------------------------------------------
// Fused aggregate + GEMM + relu.
// Block = 2 waves = 32 rows; grid = 100000/32 = 3125 exactly (no edge guards).
//
// R9 (this round): Phase A is dependency-chain latency-bound (R8 post-mortem:
// occupancy stayed ~27% despite finer blocks; nothing saturated). Changes:
//   - Per row, bins pairs 0..3 (64B, always within the CAP=32 padded slot
//     array) are loaded unconditionally as 4x int4 at FIXED addresses (no
//     index dependency, no clamping). Edges >= deg get val=0 and gather
//     col0's already-hot line -> ~free. Rows with deg<=8 (85%) are fully
//     branchless: ONE bins round-trip + ONE gather round-trip.
//   - Software-pipeline depth 1: row t+1's bins loads are issued before row
//     t's gathers are consumed -> bins latency fully hidden behind gathers.
//     [R7 lesson still honored: accumulators for only ONE row live at a
//      time; do NOT interleave rows' accumulation.]
//   - Rare deg>8 remainder handled by the old 4-wide clamped loop.
//
// Phase B: mfma_f32_16x16x32_bf16; A s=0..3 from LDS (= h rows), s=4..7
// straight from global x16; B from pre-packed Wp (lane-contiguous 16B, L2).
// C/D layout: col = lane&15, row = (lane>>4)*4 + reg  [m89-verified].
// ---------------------------------------------------------------------------
__global__ __launch_bounds__(128) void fused_agg_gemm_kernel(
    const uint4* __restrict__ x16v,
    const unsigned short* __restrict__ x16s,
    const int* __restrict__ cnt,
    const int2* __restrict__ bins,
    const unsigned short* __restrict__ Wp,
    float* __restrict__ out)
{
    __shared__ uint4 lds4[2 * 256];   // wave*256 + s*64 + m*4 + q  (8 KB)

    const int tid  = threadIdx.x;
    const int wave = tid >> 6;
    const int lane = tid & 63;
    const int row0 = blockIdx.x * 32 + wave * 16;   // 3125*32 == 100000 exactly

    // ---------------- Phase A: aggregate 16 rows into LDS ----------------
    {
        const int g   = lane >> 4;      // group 0..3
        const int gl  = lane & 15;      // lane in group
        const int s_w = gl >> 2;
        const int q_w = gl & 3;

        // prefetch degree for all 4 rows of this group (independent loads)
        int dends[4];
        const int4* b2[4];
        #pragma unroll
        for (int t = 0; t < 4; t++) {
            const int n = row0 + t * 4 + g;
            int d = cnt[n];
            dends[t] = d > CAP ? CAP : d;
            b2[t] = reinterpret_cast<const int4*>(bins + (size_t)n * CAP);
        }

        // preload row 0's bins (pairs 0..3 = edges 0..7; fixed addresses)
        int4 nb0 = b2[0][0], nb1 = b2[0][1], nb2 = b2[0][2], nb3 = b2[0][3];

        #pragma unroll
        for (int t = 0; t < 4; t++) {
            const int m_local = t * 4 + g;
            const int dend = dends[t];

            const int4 c0 = nb0, c1 = nb1, c2 = nb2, c3 = nb3;
            if (t < 3) {   // issue next row's bins NOW; stays in flight
                nb0 = b2[t + 1][0]; nb1 = b2[t + 1][1];
                nb2 = b2[t + 1][2]; nb3 = b2[t + 1][3];
            }

            // unpack 8 edges; clamp col0 (may be garbage if dend==0),
            // redirect dead edges to col0's (hot) line, zero their vals
            int col0 = c0.x; col0 = col0 < 0 ? 0 : col0;
            col0 = col0 >= N_NODES ? N_NODES - 1 : col0;
            const int cc1 = (1 < dend) ? c0.z : col0;
            const int cc2 = (2 < dend) ? c1.x : col0;
            const int cc3 = (3 < dend) ? c1.z : col0;
            const int cc4 = (4 < dend) ? c2.x : col0;
            const int cc5 = (5 < dend) ? c2.z : col0;
            const int cc6 = (6 < dend) ? c3.x : col0;
            const int cc7 = (7 < dend) ? c3.z : col0;
            const float v0 = (0 < dend) ? __int_as_float(c0.y) : 0.f;
            const float v1 = (1 < dend) ? __int_as_float(c0.w) : 0.f;
            const float v2 = (2 < dend) ? __int_as_float(c1.y) : 0.f;
            const float v3 = (3 < dend) ? __int_as_float(c1.w) : 0.f;
            const float v4 = (4 < dend) ? __int_as_float(c2.y) : 0.f;
            const float v5 = (5 < dend) ? __int_as_float(c2.w) : 0.f;
            const float v6 = (6 < dend) ? __int_as_float(c3.y) : 0.f;
            const float v7 = (7 < dend) ? __int_as_float(c3.w) : 0.f;

            // all 8 gathers in flight at once
            const uint4 p0 = x16v[(size_t)col0 * 16 + gl];
            const uint4 p1 = x16v[(size_t)cc1  * 16 + gl];
            const uint4 p2 = x16v[(size_t)cc2  * 16 + gl];
            const uint4 p3 = x16v[(size_t)cc3  * 16 + gl];
            const uint4 p4 = x16v[(size_t)cc4  * 16 + gl];
            const uint4 p5 = x16v[(size_t)cc5  * 16 + gl];
            const uint4 p6 = x16v[(size_t)cc6  * 16 + gl];
            const uint4 p7 = x16v[(size_t)cc7  * 16 + gl];

            float a0, a1, a2, a3, a4, a5, a6, a7;
            a0  = v0 * bf2f(p0.x & 0xffffu) + v1 * bf2f(p1.x & 0xffffu)
                + v2 * bf2f(p2.x & 0xffffu) + v3 * bf2f(p3.x & 0xffffu)
                + v4 * bf2f(p4.x & 0xffffu) + v5 * bf2f(p5.x & 0xffffu)
                + v6 * bf2f(p6.x & 0xffffu) + v7 * bf2f(p7.x & 0xffffu);
            a1  = v0 * bf2f(p0.x >> 16)     + v1 * bf2f(p1.x >> 16)
                + v2 * bf2f(p2.x >> 16)     + v3 * bf2f(p3.x >> 16)
                + v4 * bf2f(p4.x >> 16)     + v5 * bf2f(p5.x >> 16)
                + v6 * bf2f(p6.x >> 16)     + v7 * bf2f(p7.x >> 16);
            a2  = v0 * bf2f(p0.y & 0xffffu) + v1 * bf2f(p1.y & 0xffffu)
                + v2 * bf2f(p2.y & 0xffffu) + v3 * bf2f(p3.y & 0xffffu)
                + v4 * bf2f(p4.y & 0xffffu) + v5 * bf2f(p5.y & 0xffffu)
                + v6 * bf2f(p6.y & 0xffffu) + v7 * bf2f(p7.y & 0xffffu);
            a3  = v0 * bf2f(p0.y >> 16)     + v1 * bf2f(p1.y >> 16)
                + v2 * bf2f(p2.y >> 16)     + v3 * bf2f(p3.y >> 16)
                + v4 * bf2f(p4.y >> 16)     + v5 * bf2f(p5.y >> 16)
                + v6 * bf2f(p6.y >> 16)     + v7 * bf2f(p7.y >> 16);
            a4  = v0 * bf2f(p0.z & 0xffffu) + v1 * bf2f(p1.z & 0xffffu)
                + v2 * bf2f(p2.z & 0xffffu) + v3 * bf2f(p3.z & 0xffffu)
                + v4 * bf2f(p4.z & 0xffffu) + v5 * bf2f(p5.z & 0xffffu)
                + v6 * bf2f(p6.z & 0xffffu) + v7 * bf2f(p7.z & 0xffffu);
            a5  = v0 * bf2f(p0.z >> 16)     + v1 * bf2f(p1.z >> 16)
                + v2 * bf2f(p2.z >> 16)     + v3 * bf2f(p3.z >> 16)
                + v4 * bf2f(p4.z >> 16)     + v5 * bf2f(p5.z >> 16)
                + v6 * bf2f(p6.z >> 16)     + v7 * bf2f(p7.z >> 16);
            a6  = v0 * bf2f(p0.w & 0xffffu) + v1 * bf2f(p1.w & 0xffffu)
                + v2 * bf2f(p2.w & 0xffffu) + v3 * bf2f(p3.w & 0xffffu)
                + v4 * bf2f(p4.w & 0xffffu) + v5 * bf2f(p5.w & 0xffffu)
                + v6 * bf2f(p6.w & 0xffffu) + v7 * bf2f(p7.w & 0xffffu);
            a7  = v0 * bf2f(p0.w >> 16)     + v1 * bf2f(p1.w >> 16)
                + v2 * bf2f(p2.w >> 16)     + v3 * bf2f(p3.w >> 16)
                + v4 * bf2f(p4.w >> 16)     + v5 * bf2f(p5.w >> 16)
                + v6 * bf2f(p6.w >> 16)     + v7 * bf2f(p7.w >> 16);

            // rare heavy rows (deg > 8): old 4-wide clamped loop
            if (dend > 8) {
                const int2* bp = bins + (size_t)(row0 + m_local) * CAP;
                for (int i = 8; i < dend; i += 4) {
                    const int i1 = (i + 1 < dend) ? i + 1 : dend - 1;
                    const int i2 = (i + 2 < dend) ? i + 2 : dend - 1;
                    const int i3 = (i + 3 < dend) ? i + 3 : dend - 1;
                    int2 e0 = bp[i];
                    int2 e1 = bp[i1];
                    int2 e2 = bp[i2];
                    int2 e3 = bp[i3];
                    uint4 q0 = x16v[(size_t)e0.x * 16 + gl];
                    uint4 q1 = x16v[(size_t)e1.x * 16 + gl];
                    uint4 q2 = x16v[(size_t)e2.x * 16 + gl];
                    uint4 q3 = x16v[(size_t)e3.x * 16 + gl];
                    float w0 = __int_as_float(e0.y);
                    float w1 = (i + 1 < dend) ? __int_as_float(e1.y) : 0.f;
                    float w2 = (i + 2 < dend) ? __int_as_float(e2.y) : 0.f;
                    float w3 = (i + 3 < dend) ? __int_as_float(e3.y) : 0.f;
                    a0 += w0 * bf2f(q0.x & 0xffffu) + w1 * bf2f(q1.x & 0xffffu)
                        + w2 * bf2f(q2.x & 0xffffu) + w3 * bf2f(q3.x & 0xffffu);
                    a1 += w0 * bf2f(q0.x >> 16)     + w1 * bf2f(q1.x >> 16)
                        + w2 * bf2f(q2.x >> 16)     + w3 * bf2f(q3.x >> 16);
                    a2 += w0 * bf2f(q0.y & 0xffffu) + w1 * bf2f(q1.y & 0xffffu)
                        + w2 * bf2f(q2.y & 0xffffu) + w3 * bf2f(q3.y & 0xffffu);
                    a3 += w0 * bf2f(q0.y >> 16)     + w1 * bf2f(q1.y >> 16)
                        + w2 * bf2f(q2.y >> 16)     + w3 * bf2f(q3.y >> 16);
                    a4 += w0 * bf2f(q0.z & 0xffffu) + w1 * bf2f(q1.z & 0xffffu)
                        + w2 * bf2f(q2.z & 0xffffu) + w3 * bf2f(q3.z & 0xffffu);
                    a5 += w0 * bf2f(q0.z >> 16)     + w1 * bf2f(q1.z >> 16)
                        + w2 * bf2f(q2.z >> 16)     + w3 * bf2f(q3.z >> 16);
                    a6 += w0 * bf2f(q0.w & 0xffffu) + w1 * bf2f(q1.w & 0xffffu)
                        + w2 * bf2f(q2.w & 0xffffu) + w3 * bf2f(q3.w & 0xffffu);
                    a7 += w0 * bf2f(q0.w >> 16)     + w1 * bf2f(q1.w >> 16)
                        + w2 * bf2f(q2.w >> 16)     + w3 * bf2f(q3.w >> 16);
                }
            }

            uint4 o;
            o.x = (unsigned int)f2bf(a0) | ((unsigned int)f2bf(a1) << 16);
            o.y = (unsigned int)f2bf(a2) | ((unsigned int)f2bf(a3) << 16);
            o.z = (unsigned int)f2bf(a4) | ((unsigned int)f2bf(a5) << 16);
            o.w = (unsigned int)f2bf(a6) | ((unsigned int)f2bf(a7) << 16);
            lds4[wave * 256 + s_w * 64 + m_local * 4 + q_w] = o;
        }
    }
    __syncthreads();

    // ---------------- Phase B: MFMA GEMM + relu ----------------
    const int m    = lane & 15;
    const int quad = lane >> 4;

    const unsigned short* xrow = x16s + (size_t)(row0 + m) * D + quad * 8;

    float4v acc[8];
    #pragma unroll
    for (int jt = 0; jt < 8; jt++) acc[jt] = (float4v){0.f, 0.f, 0.f, 0.f};

    #pragma unroll
    for (int s = 0; s < 8; s++) {
        short8 a;
        if (s < 4)
            a = *reinterpret_cast<const short8*>(&lds4[wave * 256 + s * 64 + m * 4 + quad]);
        else
            a = *reinterpret_cast<const short8*>(xrow + (s - 4) * 32);
        #pragma unroll
        for (int jt = 0; jt < 8; jt++) {
            short8 b = *reinterpret_cast<const short8*>(
                Wp + ((size_t)((s * 8 + jt) * 64 + lane)) * 8);
            acc[jt] = __builtin_amdgcn_mfma_f32_16x16x32_bf16(a, b, acc[jt], 0, 0, 0);
        }
    }

    #pragma unroll
    for (int reg = 0; reg < 4; reg++) {
        const int r = row0 + quad * 4 + reg;
        float* orow = out + (size_t)r * D;
        #pragma unroll
        for (int jt = 0; jt < 8; jt++)
            orow[jt * 16 + m] = fmaxf(acc[jt][reg], 0.f);
    }
}

// ---------------------------------------------------------------------------
extern "C" void kernel_launch(void* const* d_in, const int* in_sizes, int n_in,
                              void* d_out, int out_size, void* d_ws, size_t ws_size,
                              hipStream_t stream)
{
    const float* x    = (const float*)d_in[0];
    const int*   rows = (const int*)  d_in[1];
    const int*   cols = (const int*)  d_in[2];
    const float* vals = (const float*)d_in[3];
    const float* W    = (const float*)d_in[4];
    float* out = (float*)d_out;

    char* ws = (char*)d_ws;
    uint4*          x16v = (uint4*)         (ws + X16_OFF);
    unsigned short* x16s = (unsigned short*)(ws + X16_OFF);
    unsigned short* Wp   = (unsigned short*)(ws + WP_OFF);
    int*            cnt  = (int*)           (ws + CNT_OFF);
    int2*           bins = (int2*)          (ws + BINS_OFF);

    hipMemsetAsync(cnt, 0, N_NODES * sizeof(int), stream);
    prep_kernel<<<2048, 256, 0, stream>>>(x, x16v, W, Wp, rows, cols, vals, cnt, bins);
    fused_agg_gemm_kernel<<<N_NODES / 32, 128, 0, stream>>>(
        x16v, x16s, cnt, bins, Wp, out);
}

// Round 3
// 182.563 us; speedup vs baseline: 1.0820x; 1.0142x over previous
//
#include <hip/hip_runtime.h>
#include <hip/hip_bf16.h>

constexpr int N_NODES = 100000;
constexpr int N_EDGES = 600000;
constexpr int D = 128;          // feature dim; OUT_DIM is also 128
constexpr int CAP = 32;         // slots per row; max degree ~20 (Poisson l=6)
constexpr int NPASS = 8;        // binning passes; 100000/8 = 12500 rows/pass
constexpr int ROWS_PER_PASS = N_NODES / NPASS;

// ---------------- workspace layout (bytes) ----------------
constexpr size_t X16_OFF  = 0;          // x bf16: 100000*128*2 = 25,600,000
constexpr size_t WP_OFF   = 25600000;   // packed W bf16: 65,536
constexpr size_t CNT_OFF  = 25665536;   // cnt: 100000 ints = 400,000
constexpr size_t BINS_OFF = 26065536;   // int2 x 100000*32 = 25.6 MB (end ~51.7 MB)

typedef __attribute__((ext_vector_type(8))) short short8;
typedef __attribute__((ext_vector_type(4))) float float4v;

__device__ inline unsigned short f2bf(float f) {
    union { float f; unsigned int u; } v; v.f = f;
    unsigned int u = v.u + 0x7fffu + ((v.u >> 16) & 1u);  // RNE
    return (unsigned short)(u >> 16);
}
__device__ inline float bf2f(unsigned int lo16) {
    union { unsigned int u; float f; } v; v.u = lo16 << 16;
    return v.f;
}

// ---------------------------------------------------------------------------
// Prep (one dispatch, grid-stride; cnt pre-zeroed by memset node).
// R10 reorder + range-blocked binning:
//   (b) pack W    (tiny)
//   (c) cast x fp32->bf16  (streaming; runs first so blocks enter the
//       binning passes roughly together)
//   (a) bin edges in NPASS=8 passes, pass p handles rows [p*12500,(p+1)*12500).
//       Active bins region per pass = 3.2 MB -> the 8B scattered writes'
//       write-allocate lines stay cache-resident for the whole pass, so each
//       64B line is fetched+written back ~once per ROW instead of once per
//       EDGE. [R9 counters: binning was ~64 MB of random 64B HBM traffic
//       (FETCH 28.7 + WRITE 36 of prep's 62) at ~1.4 TB/s ~= 45 us — the
//       prep pole. Range-blocking targets exactly that.]
// Wp B-fragment order for mfma_f32_16x16x32_bf16:
//   b_frag[lane][j] = W[s*32 + (lane>>4)*8 + j][jt*16 + (lane&15)]
//   at linear index ((s*8 + jt)*64 + lane)*8 + j.
// ---------------------------------------------------------------------------
__global__ __launch_bounds__(256) void prep_kernel(
    const float* __restrict__ x, uint4* __restrict__ x16,
    const float* __restrict__ W, unsigned short* __restrict__ Wp,
    const int* __restrict__ rows, const int* __restrict__ cols,
    const float* __restrict__ vals,
    int* __restrict__ cnt, int2* __restrict__ bins)
{
    const int tid = blockIdx.x * 256 + threadIdx.x;
    const int T   = gridDim.x * 256;

    // (b) pack W
    for (int idx = tid; idx < 8 * 8 * 64 * 8; idx += T) {
        int j    = idx & 7;
        int lane = (idx >> 3) & 63;
        int jt   = (idx >> 9) & 7;
        int s    = idx >> 12;
        int k = s * 32 + (lane >> 4) * 8 + j;
        int n = jt * 16 + (lane & 15);
        Wp[idx] = f2bf(W[k * 128 + n]);
    }

    // (c) cast x
    for (int g = tid; g < N_NODES * D / 8; g += T) {
        const float4* xp = reinterpret_cast<const float4*>(x + (size_t)g * 8);
        float4 a = xp[0], c = xp[1];
        uint4 o;
        o.x = (unsigned int)f2bf(a.x) | ((unsigned int)f2bf(a.y) << 16);
        o.y = (unsigned int)f2bf(a.z) | ((unsigned int)f2bf(a.w) << 16);
        o.z = (unsigned int)f2bf(c.x) | ((unsigned int)f2bf(c.y) << 16);
        o.w = (unsigned int)f2bf(c.z) | ((unsigned int)f2bf(c.w) << 16);
        x16[g] = o;
    }

    // (a) range-blocked positional binning (8 passes, disjoint row ranges,
    //     no inter-pass sync needed)
    for (int pass = 0; pass < NPASS; pass++) {
        const int rlo = pass * ROWS_PER_PASS;
        const int rhi = rlo + ROWS_PER_PASS;
        for (int e = tid; e < N_EDGES; e += T) {
            int r = rows[e];
            if (r >= rlo && r < rhi) {
                int pos = atomicAdd(&cnt[r], 1);
                if (pos < CAP)
                    bins[(size_t)r * CAP + pos] =
                        make_int2(cols[e], __float_as_int(vals[e]));
            }
        }
    }
}

// ---------------------------------------------------------------------------
// Fused aggregate + GEMM + relu.  (unchanged from R9 — passing, 51.6 us)
// Block = 2 waves = 32 rows; grid = 100000/32 = 3125 exactly (no edge guards).
//
// Phase A: dependency-chain-latency-optimized. Per row, bins pairs 0..3
// (64B, always within the CAP=32 padded slots) load unconditionally as
// 4x int4 at FIXED addresses; edges >= deg get val=0 and gather col0's hot
// line. Rows deg<=8 (85%): ONE bins round-trip + ONE gather round-trip.
// Depth-1 software pipeline: row t+1's bins issued before row t's gathers
// consumed. [R7 lesson: only ONE row's accumulators live at a time.]
// Rare deg>8 handled by 4-wide clamped loop.
//
// Phase B: mfma_f32_16x16x32_bf16; A s=0..3 from LDS (= h rows), s=4..7
// straight from global x16; B from pre-packed Wp (lane-contiguous 16B, L2).
// C/D layout: col = lane&15, row = (lane>>4)*4 + reg  [m89-verified].
// ---------------------------------------------------------------------------
__global__ __launch_bounds__(128) void fused_agg_gemm_kernel(
    const uint4* __restrict__ x16v,
    const unsigned short* __restrict__ x16s,
    const int* __restrict__ cnt,
    const int2* __restrict__ bins,
    const unsigned short* __restrict__ Wp,
    float* __restrict__ out)
{
    __shared__ uint4 lds4[2 * 256];   // wave*256 + s*64 + m*4 + q  (8 KB)

    const int tid  = threadIdx.x;
    const int wave = tid >> 6;
    const int lane = tid & 63;
    const int row0 = blockIdx.x * 32 + wave * 16;   // 3125*32 == 100000 exactly

    // ---------------- Phase A: aggregate 16 rows into LDS ----------------
    {
        const int g   = lane >> 4;      // group 0..3
        const int gl  = lane & 15;      // lane in group
        const int s_w = gl >> 2;
        const int q_w = gl & 3;

        // prefetch degree for all 4 rows of this group (independent loads)
        int dends[4];
        const int4* b2[4];
        #pragma unroll
        for (int t = 0; t < 4; t++) {
            const int n = row0 + t * 4 + g;
            int d = cnt[n];
            dends[t] = d > CAP ? CAP : d;
            b2[t] = reinterpret_cast<const int4*>(bins + (size_t)n * CAP);
        }

        // preload row 0's bins (pairs 0..3 = edges 0..7; fixed addresses)
        int4 nb0 = b2[0][0], nb1 = b2[0][1], nb2 = b2[0][2], nb3 = b2[0][3];

        #pragma unroll
        for (int t = 0; t < 4; t++) {
            const int m_local = t * 4 + g;
            const int dend = dends[t];

            const int4 c0 = nb0, c1 = nb1, c2 = nb2, c3 = nb3;
            if (t < 3) {   // issue next row's bins NOW; stays in flight
                nb0 = b2[t + 1][0]; nb1 = b2[t + 1][1];
                nb2 = b2[t + 1][2]; nb3 = b2[t + 1][3];
            }

            // unpack 8 edges; clamp col0 (may be garbage if dend==0),
            // redirect dead edges to col0's (hot) line, zero their vals
            int col0 = c0.x; col0 = col0 < 0 ? 0 : col0;
            col0 = col0 >= N_NODES ? N_NODES - 1 : col0;
            const int cc1 = (1 < dend) ? c0.z : col0;
            const int cc2 = (2 < dend) ? c1.x : col0;
            const int cc3 = (3 < dend) ? c1.z : col0;
            const int cc4 = (4 < dend) ? c2.x : col0;
            const int cc5 = (5 < dend) ? c2.z : col0;
            const int cc6 = (6 < dend) ? c3.x : col0;
            const int cc7 = (7 < dend) ? c3.z : col0;
            const float v0 = (0 < dend) ? __int_as_float(c0.y) : 0.f;
            const float v1 = (1 < dend) ? __int_as_float(c0.w) : 0.f;
            const float v2 = (2 < dend) ? __int_as_float(c1.y) : 0.f;
            const float v3 = (3 < dend) ? __int_as_float(c1.w) : 0.f;
            const float v4 = (4 < dend) ? __int_as_float(c2.y) : 0.f;
            const float v5 = (5 < dend) ? __int_as_float(c2.w) : 0.f;
            const float v6 = (6 < dend) ? __int_as_float(c3.y) : 0.f;
            const float v7 = (7 < dend) ? __int_as_float(c3.w) : 0.f;

            // all 8 gathers in flight at once
            const uint4 p0 = x16v[(size_t)col0 * 16 + gl];
            const uint4 p1 = x16v[(size_t)cc1  * 16 + gl];
            const uint4 p2 = x16v[(size_t)cc2  * 16 + gl];
            const uint4 p3 = x16v[(size_t)cc3  * 16 + gl];
            const uint4 p4 = x16v[(size_t)cc4  * 16 + gl];
            const uint4 p5 = x16v[(size_t)cc5  * 16 + gl];
            const uint4 p6 = x16v[(size_t)cc6  * 16 + gl];
            const uint4 p7 = x16v[(size_t)cc7  * 16 + gl];

            float a0, a1, a2, a3, a4, a5, a6, a7;
            a0  = v0 * bf2f(p0.x & 0xffffu) + v1 * bf2f(p1.x & 0xffffu)
                + v2 * bf2f(p2.x & 0xffffu) + v3 * bf2f(p3.x & 0xffffu)
                + v4 * bf2f(p4.x & 0xffffu) + v5 * bf2f(p5.x & 0xffffu)
                + v6 * bf2f(p6.x & 0xffffu) + v7 * bf2f(p7.x & 0xffffu);
            a1  = v0 * bf2f(p0.x >> 16)     + v1 * bf2f(p1.x >> 16)
                + v2 * bf2f(p2.x >> 16)     + v3 * bf2f(p3.x >> 16)
                + v4 * bf2f(p4.x >> 16)     + v5 * bf2f(p5.x >> 16)
                + v6 * bf2f(p6.x >> 16)     + v7 * bf2f(p7.x >> 16);
            a2  = v0 * bf2f(p0.y & 0xffffu) + v1 * bf2f(p1.y & 0xffffu)
                + v2 * bf2f(p2.y & 0xffffu) + v3 * bf2f(p3.y & 0xffffu)
                + v4 * bf2f(p4.y & 0xffffu) + v5 * bf2f(p5.y & 0xffffu)
                + v6 * bf2f(p6.y & 0xffffu) + v7 * bf2f(p7.y & 0xffffu);
            a3  = v0 * bf2f(p0.y >> 16)     + v1 * bf2f(p1.y >> 16)
                + v2 * bf2f(p2.y >> 16)     + v3 * bf2f(p3.y >> 16)
                + v4 * bf2f(p4.y >> 16)     + v5 * bf2f(p5.y >> 16)
                + v6 * bf2f(p6.y >> 16)     + v7 * bf2f(p7.y >> 16);
            a4  = v0 * bf2f(p0.z & 0xffffu) + v1 * bf2f(p1.z & 0xffffu)
                + v2 * bf2f(p2.z & 0xffffu) + v3 * bf2f(p3.z & 0xffffu)
                + v4 * bf2f(p4.z & 0xffffu) + v5 * bf2f(p5.z & 0xffffu)
                + v6 * bf2f(p6.z & 0xffffu) + v7 * bf2f(p7.z & 0xffffu);
            a5  = v0 * bf2f(p0.z >> 16)     + v1 * bf2f(p1.z >> 16)
                + v2 * bf2f(p2.z >> 16)     + v3 * bf2f(p3.z >> 16)
                + v4 * bf2f(p4.z >> 16)     + v5 * bf2f(p5.z >> 16)
                + v6 * bf2f(p6.z >> 16)     + v7 * bf2f(p7.z >> 16);
            a6  = v0 * bf2f(p0.w & 0xffffu) + v1 * bf2f(p1.w & 0xffffu)
                + v2 * bf2f(p2.w & 0xffffu) + v3 * bf2f(p3.w & 0xffffu)
                + v4 * bf2f(p4.w & 0xffffu) + v5 * bf2f(p5.w & 0xffffu)
                + v6 * bf2f(p6.w & 0xffffu) + v7 * bf2f(p7.w & 0xffffu);
            a7  = v0 * bf2f(p0.w >> 16)     + v1 * bf2f(p1.w >> 16)
                + v2 * bf2f(p2.w >> 16)     + v3 * bf2f(p3.w >> 16)
                + v4 * bf2f(p4.w >> 16)     + v5 * bf2f(p5.w >> 16)
                + v6 * bf2f(p6.w >> 16)     + v7 * bf2f(p7.w >> 16);

            // rare heavy rows (deg > 8): old 4-wide clamped loop
            if (dend > 8) {
                const int2* bp = bins + (size_t)(row0 + m_local) * CAP;
                for (int i = 8; i < dend; i += 4) {
                    const int i1 = (i + 1 < dend) ? i + 1 : dend - 1;
                    const int i2 = (i + 2 < dend) ? i + 2 : dend - 1;
                    const int i3 = (i + 3 < dend) ? i + 3 : dend - 1;
                    int2 e0 = bp[i];
                    int2 e1 = bp[i1];
                    int2 e2 = bp[i2];
                    int2 e3 = bp[i3];
                    uint4 q0 = x16v[(size_t)e0.x * 16 + gl];
                    uint4 q1 = x16v[(size_t)e1.x * 16 + gl];
                    uint4 q2 = x16v[(size_t)e2.x * 16 + gl];
                    uint4 q3 = x16v[(size_t)e3.x * 16 + gl];
                    float w0 = __int_as_float(e0.y);
                    float w1 = (i + 1 < dend) ? __int_as_float(e1.y) : 0.f;
                    float w2 = (i + 2 < dend) ? __int_as_float(e2.y) : 0.f;
                    float w3 = (i + 3 < dend) ? __int_as_float(e3.y) : 0.f;
                    a0 += w0 * bf2f(q0.x & 0xffffu) + w1 * bf2f(q1.x & 0xffffu)
                        + w2 * bf2f(q2.x & 0xffffu) + w3 * bf2f(q3.x & 0xffffu);
                    a1 += w0 * bf2f(q0.x >> 16)     + w1 * bf2f(q1.x >> 16)
                        + w2 * bf2f(q2.x >> 16)     + w3 * bf2f(q3.x >> 16);
                    a2 += w0 * bf2f(q0.y & 0xffffu) + w1 * bf2f(q1.y & 0xffffu)
                        + w2 * bf2f(q2.y & 0xffffu) + w3 * bf2f(q3.y & 0xffffu);
                    a3 += w0 * bf2f(q0.y >> 16)     + w1 * bf2f(q1.y >> 16)
                        + w2 * bf2f(q2.y >> 16)     + w3 * bf2f(q3.y >> 16);
                    a4 += w0 * bf2f(q0.z & 0xffffu) + w1 * bf2f(q1.z & 0xffffu)
                        + w2 * bf2f(q2.z & 0xffffu) + w3 * bf2f(q3.z & 0xffffu);
                    a5 += w0 * bf2f(q0.z >> 16)     + w1 * bf2f(q1.z >> 16)
                        + w2 * bf2f(q2.z >> 16)     + w3 * bf2f(q3.z >> 16);
                    a6 += w0 * bf2f(q0.w & 0xffffu) + w1 * bf2f(q1.w & 0xffffu)
                        + w2 * bf2f(q2.w & 0xffffu) + w3 * bf2f(q3.w & 0xffffu);
                    a7 += w0 * bf2f(q0.w >> 16)     + w1 * bf2f(q1.w >> 16)
                        + w2 * bf2f(q2.w >> 16)     + w3 * bf2f(q3.w >> 16);
                }
            }

            uint4 o;
            o.x = (unsigned int)f2bf(a0) | ((unsigned int)f2bf(a1) << 16);
            o.y = (unsigned int)f2bf(a2) | ((unsigned int)f2bf(a3) << 16);
            o.z = (unsigned int)f2bf(a4) | ((unsigned int)f2bf(a5) << 16);
            o.w = (unsigned int)f2bf(a6) | ((unsigned int)f2bf(a7) << 16);
            lds4[wave * 256 + s_w * 64 + m_local * 4 + q_w] = o;
        }
    }
    __syncthreads();

    // ---------------- Phase B: MFMA GEMM + relu ----------------
    const int m    = lane & 15;
    const int quad = lane >> 4;

    const unsigned short* xrow = x16s + (size_t)(row0 + m) * D + quad * 8;

    float4v acc[8];
    #pragma unroll
    for (int jt = 0; jt < 8; jt++) acc[jt] = (float4v){0.f, 0.f, 0.f, 0.f};

    #pragma unroll
    for (int s = 0; s < 8; s++) {
        short8 a;
        if (s < 4)
            a = *reinterpret_cast<const short8*>(&lds4[wave * 256 + s * 64 + m * 4 + quad]);
        else
            a = *reinterpret_cast<const short8*>(xrow + (s - 4) * 32);
        #pragma unroll
        for (int jt = 0; jt < 8; jt++) {
            short8 b = *reinterpret_cast<const short8*>(
                Wp + ((size_t)((s * 8 + jt) * 64 + lane)) * 8);
            acc[jt] = __builtin_amdgcn_mfma_f32_16x16x32_bf16(a, b, acc[jt], 0, 0, 0);
        }
    }

    #pragma unroll
    for (int reg = 0; reg < 4; reg++) {
        const int r = row0 + quad * 4 + reg;
        float* orow = out + (size_t)r * D;
        #pragma unroll
        for (int jt = 0; jt < 8; jt++)
            orow[jt * 16 + m] = fmaxf(acc[jt][reg], 0.f);
    }
}

// ---------------------------------------------------------------------------
extern "C" void kernel_launch(void* const* d_in, const int* in_sizes, int n_in,
                              void* d_out, int out_size, void* d_ws, size_t ws_size,
                              hipStream_t stream)
{
    const float* x    = (const float*)d_in[0];
    const int*   rows = (const int*)  d_in[1];
    const int*   cols = (const int*)  d_in[2];
    const float* vals = (const float*)d_in[3];
    const float* W    = (const float*)d_in[4];
    float* out = (float*)d_out;

    char* ws = (char*)d_ws;
    uint4*          x16v = (uint4*)         (ws + X16_OFF);
    unsigned short* x16s = (unsigned short*)(ws + X16_OFF);
    unsigned short* Wp   = (unsigned short*)(ws + WP_OFF);
    int*            cnt  = (int*)           (ws + CNT_OFF);
    int2*           bins = (int2*)          (ws + BINS_OFF);

    hipMemsetAsync(cnt, 0, N_NODES * sizeof(int), stream);
    prep_kernel<<<2048, 256, 0, stream>>>(x, x16v, W, Wp, rows, cols, vals, cnt, bins);
    fused_agg_gemm_kernel<<<N_NODES / 32, 128, 0, stream>>>(
        x16v, x16s, cnt, bins, Wp, out);
}